// Round 6
// baseline (132.899 us; speedup 1.0000x reference)
//
#include <hip/hip_runtime.h>

// x: [B=2, C=16, D1=8, D2=8, D3=64, D4=64] fp32
// w: [O=32, I=16, 3,3,3,3] fp32
// out = relu(conv4d_valid(x, w)): [2, 32, 6, 6, 62, 62] fp32
//
// Per tap: D[32 e4-pix][32 o] += A[pix][16 c] * B[16 c][32 o]
// (v_mfma_f32_32x32x16_bf16, fp32 acc, 81 taps).
// Barrier-free main loop, register-held A rows (6 rows serve 3 k3 via
// overlap), A/B read through L1. Occupancy is the latency-hiding engine:
// the 9 (k1,k2) phases are SPLIT across two waves (kp) per output tile
// -> 4608 waves (~18/CU). Partial accs reduced via LDS in the epilogue.

typedef __attribute__((ext_vector_type(8))) __bf16 bf16x8;
typedef __attribute__((ext_vector_type(16))) float f32x16;

#define CSTRIDE 262144  // x channel stride, elements

#define WT_OFF 0       // wT[t81][o32][c16] bf16 = 83 KB
#define XB_OFF 131072  // xb[b][d1][d2][d3][ch2][col64][c8] bf16 = 16.78 MB

// ---- prep: blocks 0..511 transform x -> xb; blocks 512..543 build wT
__global__ __launch_bounds__(256) void prep(const float* __restrict__ x,
                                            const float* __restrict__ w,
                                            unsigned char* __restrict__ ws) {
  int blk = blockIdx.x;
  if (blk < 512) {
    __bf16* xb = (__bf16*)(ws + XB_OFF);
    int n = blk * 256 + threadIdx.x;  // (b,d1,d2,d3,colgroup4)
    int cg = n & 15;
    int d3 = (n >> 4) & 63;
    int d2 = (n >> 10) & 7;
    int d1 = (n >> 13) & 7;
    int b = n >> 16;
    const float* gx =
        x + ((((b * 16) * 8 + d1) * 8 + d2) * 64 + d3) * 64 + cg * 4;
    float4 v[16];
#pragma unroll
    for (int c = 0; c < 16; ++c)
      v[c] = *(const float4*)(gx + (size_t)c * CSTRIDE);
    __bf16* row = xb + ((((b * 8 + d1) * 8 + d2) * 64 + d3) * 1024);
#pragma unroll
    for (int ch = 0; ch < 2; ++ch) {
#pragma unroll
      for (int j = 0; j < 4; ++j) {
        bf16x8 o;
#pragma unroll
        for (int cc = 0; cc < 8; ++cc)
          o[cc] = (__bf16)(((const float*)&v[ch * 8 + cc])[j]);
        *(bf16x8*)(row + ch * 512 + (cg * 4 + j) * 8) = o;
      }
    }
  } else {
    int o = blk - 512;
    __bf16* wT = (__bf16*)(ws + WT_OFF);
#pragma unroll
    for (int base = 0; base < 1296; base += 256) {
      int idx = base + threadIdx.x;
      if (idx < 1296) {
        int c = idx / 81, t = idx % 81;
        wT[t * 512 + o * 16 + c] = (__bf16)w[o * 1296 + idx];
      }
    }
  }
}

// block = (b,e1,e2, 4 e3-rows); waves: th = e4 half, kp = tap-set half
__global__ __launch_bounds__(256, 4) void conv_mfma(
    const unsigned char* __restrict__ ws, float* __restrict__ out) {
  const unsigned char* wTb = ws + WT_OFF;
  const unsigned char* xbb = ws + XB_OFF;

  int bid = blockIdx.x;
  int g = bid % 72;      // (b,e1,e2): fixed XCD per group (72 % 8 == 0)
  int chunk = bid / 72;  // 16 chunks of 4 rows (chunk 15: rows 60-61 live)
  int b = g / 36;
  int e1 = (g / 6) % 6;
  int e2 = g % 6;
  int r0 = chunk * 4;

  int lane = threadIdx.x & 63;
  int wave = threadIdx.x >> 6;
  int th = wave & 1;   // e4 half
  int kp = wave >> 1;  // tap-set half (phases 0-3 vs 4-8)
  int m32 = lane & 31;
  int half = lane >> 5;

  // per-lane byte offsets: A (pixel col + channel half), B (o + c-half)
  int aoff = half * 1024 + (th * 32 + m32) * 16;
  int woff = m32 * 32 + half * 16;

  f32x16 acc[4];
#pragma unroll
  for (int i = 0; i < 4; ++i)
#pragma unroll
    for (int r = 0; r < 16; ++r) acc[i][r] = 0.f;

  int p0 = kp ? 4 : 0;
  int p1 = kp ? 9 : 4;
  for (int p = p0; p < p1; ++p) {  // phase = (k1,k2)
    int k1 = (p >= 3) + (p >= 6);
    int k2 = p - k1 * 3;
    const unsigned char* abase =
        xbb + (size_t)(((b * 8 + e1 + k1) * 8 + e2 + k2) * 64 + r0) * 2048 +
        aoff;
    const unsigned char* wbase = wTb + p * 9216 + woff;
#pragma unroll
    for (int k4 = 0; k4 < 3; ++k4) {
      // 6 row-frags serve all (k3, i) with i + k3 = j  (k3 overlap)
      bf16x8 arow[6];
#pragma unroll
      for (int j = 0; j < 6; ++j)
        arow[j] = *(const bf16x8*)(abase + j * 2048 + k4 * 16);
#pragma unroll
      for (int k3 = 0; k3 < 3; ++k3) {
        bf16x8 bf = *(const bf16x8*)(wbase + (k3 * 3 + k4) * 1024);
#pragma unroll
        for (int i = 0; i < 4; ++i)
          acc[i] = __builtin_amdgcn_mfma_f32_32x32x16_bf16(arow[i + k3], bf,
                                                           acc[i], 0, 0, 0);
      }
    }
  }

  // ---- epilogue: kp=1 dumps partial to LDS, kp=0 adds, ReLU, store
  __shared__ float sc[2][32 * 33];  // per-th region, stride 33 conflict-free
  float* s = sc[th];
  int e4 = th * 32 + m32;
  size_t obase =
      ((((size_t)b * 32) * 6 + e1) * 6 + e2) * 3844;
#pragma unroll
  for (int i = 0; i < 4; ++i) {
    __syncthreads();  // protects region reuse from previous tile's store
    if (kp == 1) {
#pragma unroll
      for (int r = 0; r < 16; ++r) {
        int m = (r & 3) + 8 * (r >> 2) + 4 * half;  // pixel row in tile
        s[m * 33 + m32] = acc[i][r];
      }
    }
    __syncthreads();
    if (kp == 0) {
#pragma unroll
      for (int r = 0; r < 16; ++r) {
        int m = (r & 3) + 8 * (r >> 2) + 4 * half;
        s[m * 33 + m32] += acc[i][r];  // same-lane cells as kp=1's writes
      }
      int e3 = r0 + i;
      if (e3 < 62) {
        // cross-lane reads below are same-wave (LDS ops wave-ordered)
#pragma unroll
        for (int it = 0; it < 16; ++it) {
          int o = it * 2 + half;
          float v = fmaxf(s[m32 * 33 + o], 0.f);
          if (e4 < 62)
            out[obase + (size_t)o * 138384 + (size_t)e3 * 62 + e4] = v;
        }
      }
    }
  }
}

extern "C" void kernel_launch(void* const* d_in, const int* in_sizes, int n_in,
                              void* d_out, int out_size, void* d_ws,
                              size_t ws_size, hipStream_t stream) {
  const float* x = (const float*)d_in[0];
  const float* w = (const float*)d_in[1];
  float* out = (float*)d_out;
  unsigned char* ws = (unsigned char*)d_ws;
  prep<<<dim3(544), dim3(256), 0, stream>>>(x, w, ws);
  conv_mfma<<<dim3(16 * 72), dim3(256), 0, stream>>>(ws, out);
}

// Round 7
// 130.344 us; speedup vs baseline: 1.0196x; 1.0196x over previous
//
#include <hip/hip_runtime.h>

// x: [B=2, C=16, D1=8, D2=8, D3=64, D4=64] fp32
// w: [O=32, I=16, 3,3,3,3] fp32
// out = relu(conv4d_valid(x, w)): [2, 32, 6, 6, 62, 62] fp32
//
// Per tap: D[32 e4-pix][32 o] += A[pix][16 c] * B[16 c][32 o]
// (v_mfma_f32_32x32x16_bf16, fp32 acc, 81 taps).
// Explicit register-level software pipeline: step (p,k4) issues the loads
// for step+1 into the ping buffer, then MFMAs on the pong buffer. Loads are
// always one full 12-MFMA block ahead -> L1/L2 latency covered. No LDS
// staging, no __syncthreads. __launch_bounds__(256,2): spend regs on ILP.

typedef __attribute__((ext_vector_type(8))) __bf16 bf16x8;
typedef __attribute__((ext_vector_type(16))) float f32x16;

#define CSTRIDE 262144  // x channel stride, elements

#define WT_OFF 0       // wT[t81][o32][c16] bf16 = 83 KB
#define XB_OFF 131072  // xb[b][d1][d2][d3][ch2][col64][c8] bf16 = 16.78 MB

// ---- prep: blocks 0..511 transform x -> xb; blocks 512..543 build wT
__global__ __launch_bounds__(256) void prep(const float* __restrict__ x,
                                            const float* __restrict__ w,
                                            unsigned char* __restrict__ ws) {
  int blk = blockIdx.x;
  if (blk < 512) {
    __bf16* xb = (__bf16*)(ws + XB_OFF);
    int n = blk * 256 + threadIdx.x;  // (b,d1,d2,d3,colgroup4)
    int cg = n & 15;
    int d3 = (n >> 4) & 63;
    int d2 = (n >> 10) & 7;
    int d1 = (n >> 13) & 7;
    int b = n >> 16;
    const float* gx =
        x + ((((b * 16) * 8 + d1) * 8 + d2) * 64 + d3) * 64 + cg * 4;
    float4 v[16];
#pragma unroll
    for (int c = 0; c < 16; ++c)
      v[c] = *(const float4*)(gx + (size_t)c * CSTRIDE);
    __bf16* row = xb + ((((b * 8 + d1) * 8 + d2) * 64 + d3) * 1024);
#pragma unroll
    for (int ch = 0; ch < 2; ++ch) {
#pragma unroll
      for (int j = 0; j < 4; ++j) {
        bf16x8 o;
#pragma unroll
        for (int cc = 0; cc < 8; ++cc)
          o[cc] = (__bf16)(((const float*)&v[ch * 8 + cc])[j]);
        *(bf16x8*)(row + ch * 512 + (cg * 4 + j) * 8) = o;
      }
    }
  } else {
    int o = blk - 512;
    __bf16* wT = (__bf16*)(ws + WT_OFF);
#pragma unroll
    for (int base = 0; base < 1296; base += 256) {
      int idx = base + threadIdx.x;
      if (idx < 1296) {
        int c = idx / 81, t = idx % 81;
        wT[t * 512 + o * 16 + c] = (__bf16)w[o * 1296 + idx];
      }
    }
  }
}

// block = (b,e1,e2, 8 e3-rows); 4 waves = th(e4 half) x rg(4-row group)
__global__ __launch_bounds__(256, 2) void conv_mfma(
    const unsigned char* __restrict__ ws, float* __restrict__ out) {
  const unsigned char* wTb = ws + WT_OFF;
  const unsigned char* xbb = ws + XB_OFF;

  int bid = blockIdx.x;
  int g = bid % 72;      // (b,e1,e2)
  int chunk = bid / 72;  // 8 chunks of 8 e3-rows (chunk 7: rows 56-61 live)
  int b = g / 36;
  int e1 = (g / 6) % 6;
  int e2 = g % 6;
  int r0 = chunk * 8;

  int lane = threadIdx.x & 63;
  int wave = threadIdx.x >> 6;
  int th = wave & 1;   // e4 half
  int rg = wave >> 1;  // 4-row group
  int m32 = lane & 31;
  int half = lane >> 5;

  // per-lane byte offsets: A (pixel col + channel half), B (o + c-half)
  int aoff = half * 1024 + (th * 32 + m32) * 16;
  int woff = m32 * 32 + half * 16;

  // block-uniform A base for phase p: abase0 + (k1*8 + k2) * 131072
  const unsigned char* abase0 =
      xbb + (size_t)(((b * 8 + e1) * 8 + e2) * 64 + r0 + rg * 4) * 2048 + aoff;
  const unsigned char* wbase = wTb + woff;

  f32x16 acc[4];
#pragma unroll
  for (int i = 0; i < 4; ++i)
#pragma unroll
    for (int r = 0; r < 16; ++r) acc[i][r] = 0.f;

  bf16x8 ab[2][6];  // A rows, ping-pong per (p,k4) step
  bf16x8 bb[2][9];  // B frags, ping-pong per phase

  // prologue: fill step-0 buffers (phase 0, k4 = 0)
#pragma unroll
  for (int j = 0; j < 6; ++j)
    ab[0][j] = *(const bf16x8*)(abase0 + j * 2048);
#pragma unroll
  for (int t9 = 0; t9 < 9; ++t9)
    bb[0][t9] = *(const bf16x8*)(wbase + t9 * 1024);

#pragma unroll
  for (int p = 0; p < 9; ++p) {  // phase = (k1,k2), fully unrolled
    const int k1 = p / 3, k2 = p % 3;
    const unsigned char* acur = abase0 + (k1 * 8 + k2) * 131072;
#pragma unroll
    for (int k4 = 0; k4 < 3; ++k4) {
      const int sc = (p * 3 + k4) & 1, sn = sc ^ 1;  // step ping-pong
      // ---- prefetch next step's A (and B at phase boundary)
      if (k4 < 2) {
#pragma unroll
        for (int j = 0; j < 6; ++j)
          ab[sn][j] = *(const bf16x8*)(acur + j * 2048 + (k4 + 1) * 16);
      } else if (p < 8) {
        const int nk1 = (p + 1) / 3, nk2 = (p + 1) % 3;
        const unsigned char* anxt = abase0 + (nk1 * 8 + nk2) * 131072;
#pragma unroll
        for (int j = 0; j < 6; ++j)
          ab[sn][j] = *(const bf16x8*)(anxt + j * 2048);
#pragma unroll
        for (int t9 = 0; t9 < 9; ++t9)
          bb[(p + 1) & 1][t9] =
              *(const bf16x8*)(wbase + (p + 1) * 9216 + t9 * 1024);
      }
      // ---- compute current step: 3 k3 x 4 tiles on the pong buffers
#pragma unroll
      for (int k3 = 0; k3 < 3; ++k3) {
        bf16x8 bf = bb[p & 1][k3 * 3 + k4];
#pragma unroll
        for (int i = 0; i < 4; ++i)
          acc[i] = __builtin_amdgcn_mfma_f32_32x32x16_bf16(ab[sc][i + k3], bf,
                                                           acc[i], 0, 0, 0);
      }
    }
  }

  // ---- epilogue: per-wave LDS transpose (stride 33), ReLU, coalesced store.
  // sc region is wave-private; LDS ops within a wave are ordered -> no barrier.
  __shared__ float scr[4][32 * 33];
  float* s = scr[wave];
  int e4 = th * 32 + m32;
  size_t obase = ((((size_t)b * 32) * 6 + e1) * 6 + e2) * 3844;
#pragma unroll
  for (int i = 0; i < 4; ++i) {
    int e3 = r0 + rg * 4 + i;
#pragma unroll
    for (int r = 0; r < 16; ++r) {
      int m = (r & 3) + 8 * (r >> 2) + 4 * half;  // pixel row in tile
      s[m * 33 + m32] = acc[i][r];                // [pix][o]
    }
    if (e3 < 62) {
#pragma unroll
      for (int it = 0; it < 16; ++it) {
        int o = it * 2 + half;
        float v = fmaxf(s[m32 * 33 + o], 0.f);
        if (e4 < 62)
          out[obase + (size_t)o * 138384 + (size_t)e3 * 62 + e4] = v;
      }
    }
  }
}

extern "C" void kernel_launch(void* const* d_in, const int* in_sizes, int n_in,
                              void* d_out, int out_size, void* d_ws,
                              size_t ws_size, hipStream_t stream) {
  const float* x = (const float*)d_in[0];
  const float* w = (const float*)d_in[1];
  float* out = (float*)d_out;
  unsigned char* ws = (unsigned char*)d_ws;
  prep<<<dim3(544), dim3(256), 0, stream>>>(x, w, ws);
  conv_mfma<<<dim3(8 * 72), dim3(256), 0, stream>>>(ws, out);
}

// Round 9
// 117.532 us; speedup vs baseline: 1.1307x; 1.1090x over previous
//
#include <hip/hip_runtime.h>

// x: [B=2, C=16, D1=8, D2=8, D3=64, D4=64] fp32
// w: [O=32, I=16, 3,3,3,3] fp32
// out = relu(conv4d_valid(x, w)): [2, 32, 6, 6, 62, 62] fp32
//
// Per tap: D[32 e4-pix][32 o] += A[pix][16 c] * B[16 c][32 o]
// (v_mfma_f32_32x32x16_bf16, fp32 acc, 81 taps).
// Wave-private LDS double-buffer, zero __syncthreads. global_load_lds has
// no dest VGPR, so the compiler CANNOT see the cp16 -> ds_read dependency
// (r8's inf). Ordering is manual: each prefetch region issues 8 cp16s
// FIRST, then 9 B-loads (regions pinned by sched_barrier(0)); vmcnt
// retires oldest-first, so `s_waitcnt vmcnt(9)` at the next phase top
// guarantees the cp16s landed while the B-loads stay in flight.

typedef __attribute__((ext_vector_type(8))) __bf16 bf16x8;
typedef __attribute__((ext_vector_type(16))) float f32x16;

#define CSTRIDE 262144  // x channel stride, elements

#define WT_OFF 0       // wT[t81][o32][c16] bf16 = 83 KB
#define XB_OFF 131072  // xb[b][d1][d2][d3][ch2][col64][c8] bf16 = 16.78 MB

typedef __attribute__((address_space(1))) const unsigned int gu32;
typedef __attribute__((address_space(3))) unsigned int lu32;

__device__ __forceinline__ void async_cp16(const void* g, void* l) {
  // HW writes lane i's 16B to ldsbase + i*16; pass uniform LDS base.
  __builtin_amdgcn_global_load_lds((gu32*)g, (lu32*)l, 16, 0, 0);
}

// wait until <=9 vmem ops outstanding: all cp16s (issued before the 9
// B-loads) have completed; B-loads may still be in flight.
__device__ __forceinline__ void wait_cp_done() {
  __builtin_amdgcn_sched_barrier(0);
  asm volatile("s_waitcnt vmcnt(9)");
  __builtin_amdgcn_sched_barrier(0);
}

// ---- prep: blocks 0..511 transform x -> xb; blocks 512..543 build wT
__global__ __launch_bounds__(256) void prep(const float* __restrict__ x,
                                            const float* __restrict__ w,
                                            unsigned char* __restrict__ ws) {
  int blk = blockIdx.x;
  if (blk < 512) {
    __bf16* xb = (__bf16*)(ws + XB_OFF);
    int n = blk * 256 + threadIdx.x;  // (b,d1,d2,d3,colgroup4)
    int cg = n & 15;
    int d3 = (n >> 4) & 63;
    int d2 = (n >> 10) & 7;
    int d1 = (n >> 13) & 7;
    int b = n >> 16;
    const float* gx =
        x + ((((b * 16) * 8 + d1) * 8 + d2) * 64 + d3) * 64 + cg * 4;
    float4 v[16];
#pragma unroll
    for (int c = 0; c < 16; ++c)
      v[c] = *(const float4*)(gx + (size_t)c * CSTRIDE);
    __bf16* row = xb + ((((b * 8 + d1) * 8 + d2) * 64 + d3) * 1024);
#pragma unroll
    for (int ch = 0; ch < 2; ++ch) {
#pragma unroll
      for (int j = 0; j < 4; ++j) {
        bf16x8 o;
#pragma unroll
        for (int cc = 0; cc < 8; ++cc)
          o[cc] = (__bf16)(((const float*)&v[ch * 8 + cc])[j]);
        *(bf16x8*)(row + ch * 512 + (cg * 4 + j) * 8) = o;
      }
    }
  } else {
    int o = blk - 512;
    __bf16* wT = (__bf16*)(ws + WT_OFF);
#pragma unroll
    for (int base = 0; base < 1296; base += 256) {
      int idx = base + threadIdx.x;
      if (idx < 1296) {
        int c = idx / 81, t = idx % 81;
        wT[t * 512 + o * 16 + c] = (__bf16)w[o * 1296 + idx];
      }
    }
  }
}

// block = 4 independent waves; wave = (b,e1,e2, 2 e3-rows, full 64 e4).
// chunk = bid%8 -> all 72 blocks of one 8-row d3-chunk on one XCD.
__global__ __launch_bounds__(256, 2) void conv_mfma(
    const unsigned char* __restrict__ ws, float* __restrict__ out) {
  const unsigned char* wTb = ws + WT_OFF;
  const unsigned char* xbb = ws + XB_OFF;

  // per wave: 2 x 8192 B A-buffers; +64B slack
  __shared__ __align__(16) unsigned char lds[4 * 16384 + 64];

  int bid = blockIdx.x;
  int chunk = bid & 7;  // 8-row d3 chunk
  int g = bid >> 3;     // (b,e1,e2)
  int b = g / 36;
  int e1 = (g / 6) % 6;
  int e2 = g % 6;

  int lane = threadIdx.x & 63;
  int wave = threadIdx.x >> 6;
  int m32 = lane & 31;
  int half = lane >> 5;
  int r0b = chunk * 8 + wave * 2;  // wave's e3 base (62/63 -> fully masked)

  unsigned char* ldsw = lds + wave * 16384;
  int ab_lane = half * 1024 + m32 * 16;
  const unsigned char* wbase = wTb + m32 * 32 + half * 16;

  f32x16 acc[4];  // (row i in {0,1}) x (e4-half th in {0,1})
#pragma unroll
  for (int i = 0; i < 4; ++i)
#pragma unroll
    for (int r = 0; r < 16; ++r) acc[i][r] = 0.f;

  bf16x8 bb[2][9];  // B frags, per-phase ping-pong

  // ---- prologue: cp16s FIRST (oldest), then B(0) loads
  __builtin_amdgcn_sched_barrier(0);
  {
    const unsigned char* base =
        xbb + (size_t)(((b * 8 + e1) * 8 + e2) * 64) * 2048;
#pragma unroll
    for (int j = 0; j < 4; ++j) {
      int row = r0b + j;
      if (row > 63) row = 63;  // clamped rows only feed masked outputs
      const unsigned char* gr = base + (size_t)row * 2048 + lane * 16;
      async_cp16(gr, ldsw + j * 2048);
      async_cp16(gr + 1024, ldsw + j * 2048 + 1024);
    }
  }
  __builtin_amdgcn_sched_barrier(0);
#pragma unroll
  for (int t9 = 0; t9 < 9; ++t9)
    bb[0][t9] = *(const bf16x8*)(wbase + t9 * 1024);

#pragma unroll
  for (int p = 0; p < 9; ++p) {  // phase = (k1,k2)
    const int cb = p & 1, nb = cb ^ 1;
    const unsigned char* abase = ldsw + cb * 8192 + ab_lane;

    wait_cp_done();  // buffer cb is staged; B-loads still in flight

    // frag(j=row, th): addr = j*2048 + th*512 + k4*16 (+ per-lane ab_lane)
    bf16x8 a0[8], a1[8], a2[8];
#pragma unroll
    for (int j = 0; j < 4; ++j)
#pragma unroll
      for (int th = 0; th < 2; ++th)
        a0[j * 2 + th] = *(const bf16x8*)(abase + j * 2048 + th * 512);
#pragma unroll
    for (int k3 = 0; k3 < 3; ++k3)
#pragma unroll
      for (int i = 0; i < 2; ++i)
#pragma unroll
        for (int th = 0; th < 2; ++th)
          acc[i * 2 + th] = __builtin_amdgcn_mfma_f32_32x32x16_bf16(
              a0[(i + k3) * 2 + th], bb[cb][k3 * 3 + 0], acc[i * 2 + th], 0, 0,
              0);
#pragma unroll
    for (int j = 0; j < 4; ++j)
#pragma unroll
      for (int th = 0; th < 2; ++th)
        a1[j * 2 + th] = *(const bf16x8*)(abase + j * 2048 + th * 512 + 16);
#pragma unroll
    for (int k3 = 0; k3 < 3; ++k3)
#pragma unroll
      for (int i = 0; i < 2; ++i)
#pragma unroll
        for (int th = 0; th < 2; ++th)
          acc[i * 2 + th] = __builtin_amdgcn_mfma_f32_32x32x16_bf16(
              a1[(i + k3) * 2 + th], bb[cb][k3 * 3 + 1], acc[i * 2 + th], 0, 0,
              0);
    // last k4's reads BEFORE the prefetch (no ds_read after the cp16s)
#pragma unroll
    for (int j = 0; j < 4; ++j)
#pragma unroll
      for (int th = 0; th < 2; ++th)
        a2[j * 2 + th] = *(const bf16x8*)(abase + j * 2048 + th * 512 + 32);

    __builtin_amdgcn_sched_barrier(0);
    // ---- prefetch p+1: cp16s first (oldest) ...
    if (p < 8) {
      const int np = p + 1;
      const int nk1 = np / 3, nk2 = np - nk1 * 3;
      const unsigned char* base =
          xbb + (size_t)(((b * 8 + e1 + nk1) * 8 + (e2 + nk2)) * 64) * 2048;
      unsigned char* dst = ldsw + nb * 8192;
#pragma unroll
      for (int j = 0; j < 4; ++j) {
        int row = r0b + j;
        if (row > 63) row = 63;
        const unsigned char* gr = base + (size_t)row * 2048 + lane * 16;
        async_cp16(gr, dst + j * 2048);
        async_cp16(gr + 1024, dst + j * 2048 + 1024);
      }
    }
    __builtin_amdgcn_sched_barrier(0);
    // ... then the 9 B-loads (younger: excluded from the vmcnt(9) wait)
    if (p < 8) {
#pragma unroll
      for (int t9 = 0; t9 < 9; ++t9)
        bb[nb][t9] = *(const bf16x8*)(wbase + (p + 1) * 9216 + t9 * 1024);
    }
    __builtin_amdgcn_sched_barrier(0);
    // mfma k4=2 (covers the prefetch just issued)
#pragma unroll
    for (int k3 = 0; k3 < 3; ++k3)
#pragma unroll
      for (int i = 0; i < 2; ++i)
#pragma unroll
        for (int th = 0; th < 2; ++th)
          acc[i * 2 + th] = __builtin_amdgcn_mfma_f32_32x32x16_bf16(
              a2[(i + k3) * 2 + th], bb[cb][k3 * 3 + 2], acc[i * 2 + th], 0, 0,
              0);
  }

  // ---- epilogue: wave-private LDS transpose (stride 33), ReLU, store.
  // Same-wave DS ops are ordered; no outstanding LDS-DMA (phase 8 waited).
  float* sc = (float*)(void*)ldsw;
  size_t obase = ((((size_t)b * 32) * 6 + e1) * 6 + e2) * 3844;
#pragma unroll
  for (int i = 0; i < 2; ++i) {
    int e3 = r0b + i;
#pragma unroll
    for (int th = 0; th < 2; ++th) {
#pragma unroll
      for (int r = 0; r < 16; ++r) {
        int m = (r & 3) + 8 * (r >> 2) + 4 * half;  // pixel row in tile
        sc[m * 33 + m32] = acc[i * 2 + th][r];      // [pix][o]
      }
      int e4 = th * 32 + m32;
      if (e3 < 62) {
#pragma unroll
        for (int it = 0; it < 16; ++it) {
          int o = it * 2 + half;
          float v = fmaxf(sc[m32 * 33 + o], 0.f);
          if (e4 < 62)
            out[obase + (size_t)o * 138384 + (size_t)e3 * 62 + e4] = v;
        }
      }
    }
  }
}

extern "C" void kernel_launch(void* const* d_in, const int* in_sizes, int n_in,
                              void* d_out, int out_size, void* d_ws,
                              size_t ws_size, hipStream_t stream) {
  const float* x = (const float*)d_in[0];
  const float* w = (const float*)d_in[1];
  float* out = (float*)d_out;
  unsigned char* ws = (unsigned char*)d_ws;
  prep<<<dim3(544), dim3(256), 0, stream>>>(x, w, ws);
  conv_mfma<<<dim3(576), dim3(256), 0, stream>>>(ws, out);
}